// Round 6
// baseline (622.503 us; speedup 1.0000x reference)
//
#include <hip/hip_runtime.h>
#include <hip/hip_fp16.h>
#include <math.h>

#define NF 128
#define NC 40

typedef unsigned short bfraw;

__device__ __forceinline__ float bfLo(unsigned u) {
  return __uint_as_float(u << 16);
}
__device__ __forceinline__ float bfHi(unsigned u) {
  return __uint_as_float(u & 0xffff0000u);
}
__device__ __forceinline__ unsigned short f2bf(float f) {
  unsigned u = __float_as_uint(f);
  u += 0x7fff + ((u >> 16) & 1);  // RNE
  return (unsigned short)(u >> 16);
}
// weight in [0,1): positive fp16, 15 bits (no sign)
__device__ __forceinline__ unsigned short f2h15(float f) {
  __half h = __float2half(f);
  __half_raw hr = static_cast<__half_raw>(h);
  return (unsigned short)(hr.x & 0x7FFF);
}
__device__ __forceinline__ float h15tof(unsigned rec) {
  __half_raw hr;
  hr.x = (unsigned short)(rec & 0x7FFF);
  __half h = static_cast<__half>(hr);
  return __half2float(h);
}

// ---------------- CSR build ----------------

__global__ __launch_bounds__(256) void count_kernel(const int* __restrict__ tgt,
                                                    int* __restrict__ cnt, int e) {
  int i = blockIdx.x * 256 + threadIdx.x;
  if (i < e) atomicAdd(&cnt[__builtin_nontemporal_load(&tgt[i])], 1);
}

__global__ __launch_bounds__(1024) void scan1_kernel(const int* __restrict__ cnt,
                                                     int* __restrict__ rp,
                                                     int* __restrict__ bsum, int n) {
  __shared__ int wsum[16];
  int tid = threadIdx.x, lane = tid & 63, wid = tid >> 6;
  int i = blockIdx.x * 1024 + tid;
  int v = (i < n) ? cnt[i] : 0;
  int x = v;
  #pragma unroll
  for (int off = 1; off < 64; off <<= 1) {
    int t = __shfl_up(x, off);
    if (lane >= off) x += t;
  }
  if (lane == 63) wsum[wid] = x;
  __syncthreads();
  if (wid == 0) {
    int ws = (lane < 16) ? wsum[lane] : 0;
    int y = ws;
    #pragma unroll
    for (int off = 1; off < 16; off <<= 1) {
      int t = __shfl_up(y, off);
      if (lane >= off) y += t;
    }
    if (lane < 16) wsum[lane] = y - ws;
  }
  __syncthreads();
  int incl = x + wsum[wid];
  if (i < n) rp[i] = incl - v;
  if (tid == 1023) bsum[blockIdx.x] = incl;
}

__global__ __launch_bounds__(1024) void scan2_kernel(int* __restrict__ bsum, int nb,
                                                     int* __restrict__ rp_n) {
  __shared__ int wsum[16];
  int tid = threadIdx.x, lane = tid & 63, wid = tid >> 6;
  int v = (tid < nb) ? bsum[tid] : 0;
  int x = v;
  #pragma unroll
  for (int off = 1; off < 64; off <<= 1) {
    int t = __shfl_up(x, off);
    if (lane >= off) x += t;
  }
  if (lane == 63) wsum[wid] = x;
  __syncthreads();
  if (wid == 0) {
    int ws = (lane < 16) ? wsum[lane] : 0;
    int y = ws;
    #pragma unroll
    for (int off = 1; off < 16; off <<= 1) {
      int t = __shfl_up(y, off);
      if (lane >= off) y += t;
    }
    if (lane < 16) wsum[lane] = y - ws;
  }
  __syncthreads();
  int incl = x + wsum[wid];
  if (tid < nb) bsum[tid] = incl - v;
  if (tid == 1023) *rp_n = incl;
}

__global__ __launch_bounds__(256) void scan3_kernel(int* __restrict__ rp,
                                                    int* __restrict__ cursor,
                                                    const int* __restrict__ bsum, int n) {
  int i = blockIdx.x * 256 + threadIdx.x;
  if (i < n) {
    int v = rp[i] + bsum[i >> 10];
    rp[i] = v;
    cursor[i] = v;
  }
}

// XCD-partitioned scatter; streaming reads NON-TEMPORAL so they don't evict
// the partially-assembled ecsr lines from this XCD's L2.
__global__ __launch_bounds__(256) void fill_kernel(const int* __restrict__ src,
                                                   const int* __restrict__ tgt,
                                                   const float* __restrict__ mw,
                                                   int* __restrict__ cursor,
                                                   unsigned* __restrict__ ecsr,
                                                   int e, int n) {
  int part = blockIdx.x & 7;
  int nset = gridDim.x >> 3;
  int lo = (int)(((long long)n * part) >> 3);
  int hi = (int)(((long long)n * (part + 1)) >> 3);
  int stride = nset * 256;
  for (int i = (blockIdx.x >> 3) * 256 + threadIdx.x; i < e; i += stride) {
    int t = __builtin_nontemporal_load(&tgt[i]);
    if (t >= lo && t < hi) {
      int pos = atomicAdd(&cursor[t], 1);
      unsigned s = (unsigned)__builtin_nontemporal_load(&src[i]);
      float w = __builtin_nontemporal_load(&mw[i]);
      ecsr[pos] = (s << 15) | f2h15(w);
    }
  }
}

// ---------------- GEMM: Tb[N,128](bf16) = X[N,128] @ W[128,128] ----------------

__global__ __launch_bounds__(256) void gemm128_kernel(const float* __restrict__ X,
                                                      const float* __restrict__ W,
                                                      bfraw* __restrict__ Tb, int n) {
  __shared__ float Xs[64][NF];
  int block_row = blockIdx.x * 64;
  int tid = threadIdx.x;
  #pragma unroll
  for (int it = 0; it < 8; ++it) {
    int flat = it * 1024 + tid * 4;
    int r = flat >> 7, c = flat & 127;
    int gr = block_row + r;
    float4 v = make_float4(0.f, 0.f, 0.f, 0.f);
    if (gr < n) v = *(const float4*)&X[(size_t)gr * NF + c];
    *(float4*)&Xs[r][c] = v;
  }
  __syncthreads();
  int cg = tid & 31;
  int rg = tid >> 5;
  float4 acc[8];
  #pragma unroll
  for (int r = 0; r < 8; ++r) acc[r] = make_float4(0.f, 0.f, 0.f, 0.f);
  for (int k = 0; k < NF; ++k) {
    float4 w = *(const float4*)&W[k * NF + cg * 4];
    #pragma unroll
    for (int r = 0; r < 8; ++r) {
      float xv = Xs[rg * 8 + r][k];
      acc[r].x += xv * w.x;
      acc[r].y += xv * w.y;
      acc[r].z += xv * w.z;
      acc[r].w += xv * w.w;
    }
  }
  #pragma unroll
  for (int r = 0; r < 8; ++r) {
    int gr = block_row + rg * 8 + r;
    if (gr < n) {
      ushort4 o;
      o.x = f2bf(acc[r].x); o.y = f2bf(acc[r].y);
      o.z = f2bf(acc[r].z); o.w = f2bf(acc[r].w);
      *(ushort4*)&Tb[(size_t)gr * NF + cg * 4] = o;
    }
  }
}

// ---------------- aggregation (pull), bf16 gather ----------------
// one wave per node; 8 edge streams x 8 lanes; each lane owns 16 features (32B)
// -> 16 gather loads in flight per wave, stride-8 loop, no tail code.

template <bool RELU, bool RES, bool BIAS, bool OUTBF>
__global__ __launch_bounds__(256) void agg128_kernel(const bfraw* __restrict__ Tb,
                                                     const int* __restrict__ rp,
                                                     const unsigned* __restrict__ ecsr,
                                                     const float* __restrict__ bias,
                                                     const float* __restrict__ Hres,
                                                     void* __restrict__ HoutV, int n) {
  int node = (blockIdx.x * 256 + threadIdx.x) >> 6;
  int lane = threadIdx.x & 63;
  if (node >= n) return;
  int st = lane >> 3;  // edge-stream 0..7
  int fl = lane & 7;   // features 16*fl .. 16*fl+15
  int beg = rp[node], end = rp[node + 1];
  float a[16];
  #pragma unroll
  for (int i = 0; i < 16; ++i) a[i] = 0.f;
  for (int eidx = beg + st; eidx < end; eidx += 8) {
    unsigned e0 = __builtin_nontemporal_load(&ecsr[eidx]);
    float w0 = h15tof(e0);
    const bfraw* row = &Tb[(size_t)(e0 >> 15) * NF + fl * 16];
    uint4 q0 = *(const uint4*)row;
    uint4 q1 = *(const uint4*)(row + 8);
    a[0]  = fmaf(w0, bfLo(q0.x), a[0]);  a[1]  = fmaf(w0, bfHi(q0.x), a[1]);
    a[2]  = fmaf(w0, bfLo(q0.y), a[2]);  a[3]  = fmaf(w0, bfHi(q0.y), a[3]);
    a[4]  = fmaf(w0, bfLo(q0.z), a[4]);  a[5]  = fmaf(w0, bfHi(q0.z), a[5]);
    a[6]  = fmaf(w0, bfLo(q0.w), a[6]);  a[7]  = fmaf(w0, bfHi(q0.w), a[7]);
    a[8]  = fmaf(w0, bfLo(q1.x), a[8]);  a[9]  = fmaf(w0, bfHi(q1.x), a[9]);
    a[10] = fmaf(w0, bfLo(q1.y), a[10]); a[11] = fmaf(w0, bfHi(q1.y), a[11]);
    a[12] = fmaf(w0, bfLo(q1.z), a[12]); a[13] = fmaf(w0, bfHi(q1.z), a[13]);
    a[14] = fmaf(w0, bfLo(q1.w), a[14]); a[15] = fmaf(w0, bfHi(q1.w), a[15]);
  }
  #pragma unroll
  for (int i = 0; i < 16; ++i) {
    a[i] += __shfl_xor(a[i], 8);
    a[i] += __shfl_xor(a[i], 16);
    a[i] += __shfl_xor(a[i], 32);
  }
  if (st == 0) {
    if (BIAS) {
      #pragma unroll
      for (int g = 0; g < 4; ++g) {
        float4 b = *(const float4*)&bias[fl * 16 + g * 4];
        a[g * 4]     += b.x; a[g * 4 + 1] += b.y;
        a[g * 4 + 2] += b.z; a[g * 4 + 3] += b.w;
      }
    }
    if (RELU) {
      #pragma unroll
      for (int i = 0; i < 16; ++i) a[i] = fmaxf(a[i], 0.f);
    }
    if (RES) {
      #pragma unroll
      for (int g = 0; g < 4; ++g) {
        float4 r = *(const float4*)&Hres[(size_t)node * NF + fl * 16 + g * 4];
        a[g * 4]     += r.x; a[g * 4 + 1] += r.y;
        a[g * 4 + 2] += r.z; a[g * 4 + 3] += r.w;
      }
    }
    if (OUTBF) {
      bfraw* Hout = (bfraw*)HoutV;
      uint4 o0, o1;
      o0.x = ((unsigned)f2bf(a[1])  << 16) | f2bf(a[0]);
      o0.y = ((unsigned)f2bf(a[3])  << 16) | f2bf(a[2]);
      o0.z = ((unsigned)f2bf(a[5])  << 16) | f2bf(a[4]);
      o0.w = ((unsigned)f2bf(a[7])  << 16) | f2bf(a[6]);
      o1.x = ((unsigned)f2bf(a[9])  << 16) | f2bf(a[8]);
      o1.y = ((unsigned)f2bf(a[11]) << 16) | f2bf(a[10]);
      o1.z = ((unsigned)f2bf(a[13]) << 16) | f2bf(a[12]);
      o1.w = ((unsigned)f2bf(a[15]) << 16) | f2bf(a[14]);
      *(uint4*)&Hout[(size_t)node * NF + fl * 16] = o0;
      *(uint4*)&Hout[(size_t)node * NF + fl * 16 + 8] = o1;
    } else {
      float* Hout = (float*)HoutV;
      #pragma unroll
      for (int g = 0; g < 4; ++g) {
        float4 o;
        o.x = a[g * 4]; o.y = a[g * 4 + 1]; o.z = a[g * 4 + 2]; o.w = a[g * 4 + 3];
        *(float4*)&Hout[(size_t)node * NF + fl * 16 + g * 4] = o;
      }
    }
  }
}

// ---------------- fused final: out = log_softmax(A@W3 + b3) ----------------

__global__ __launch_bounds__(256) void gemm40_lsm_kernel(const float* __restrict__ A,
                                                         const float* __restrict__ W,
                                                         const float* __restrict__ bias,
                                                         float* __restrict__ out, int n) {
  __shared__ float Ws[NF * NC];  // 20 KB
  int tid = threadIdx.x;
  #pragma unroll
  for (int it = 0; it < 5; ++it) {
    int off = it * 1024 + tid * 4;
    *(float4*)&Ws[off] = *(const float4*)&W[off];
  }
  __syncthreads();
  int node = blockIdx.x * 256 + tid;
  if (node >= n) return;

  float4 acc[10];
  #pragma unroll
  for (int cg = 0; cg < 10; ++cg) acc[cg] = *(const float4*)&bias[cg * 4];

  const float* arow = A + (size_t)node * NF;
  for (int k0 = 0; k0 < NF; k0 += 4) {
    float4 a4 = *(const float4*)&arow[k0];
    float av[4] = {a4.x, a4.y, a4.z, a4.w};
    #pragma unroll
    for (int j = 0; j < 4; ++j) {
      #pragma unroll
      for (int cg = 0; cg < 10; ++cg) {
        float4 w4 = *(const float4*)&Ws[(k0 + j) * NC + cg * 4];
        acc[cg].x = fmaf(av[j], w4.x, acc[cg].x);
        acc[cg].y = fmaf(av[j], w4.y, acc[cg].y);
        acc[cg].z = fmaf(av[j], w4.z, acc[cg].z);
        acc[cg].w = fmaf(av[j], w4.w, acc[cg].w);
      }
    }
  }
  float m = -INFINITY;
  #pragma unroll
  for (int cg = 0; cg < 10; ++cg) {
    m = fmaxf(m, fmaxf(fmaxf(acc[cg].x, acc[cg].y), fmaxf(acc[cg].z, acc[cg].w)));
  }
  float s = 0.f;
  #pragma unroll
  for (int cg = 0; cg < 10; ++cg) {
    s += expf(acc[cg].x - m) + expf(acc[cg].y - m) +
         expf(acc[cg].z - m) + expf(acc[cg].w - m);
  }
  float lse = m + logf(s);
  float* orow = out + (size_t)node * NC;
  #pragma unroll
  for (int cg = 0; cg < 10; ++cg) {
    float4 o;
    o.x = acc[cg].x - lse; o.y = acc[cg].y - lse;
    o.z = acc[cg].z - lse; o.w = acc[cg].w - lse;
    *(float4*)&orow[cg * 4] = o;
  }
}

// ---------------- launch ----------------

extern "C" void kernel_launch(void* const* d_in, const int* in_sizes, int n_in,
                              void* d_out, int out_size, void* d_ws, size_t ws_size,
                              hipStream_t stream) {
  const float* x   = (const float*)d_in[0];
  const int*   src = (const int*)d_in[1];
  const int*   tgt = (const int*)d_in[2];
  const float* mw  = (const float*)d_in[3];
  const float* W0  = (const float*)d_in[4];
  const float* b0  = (const float*)d_in[5];
  const float* W1  = (const float*)d_in[6];
  const float* b1  = (const float*)d_in[7];
  const float* W2  = (const float*)d_in[8];
  const float* b2  = (const float*)d_in[9];
  const float* W3  = (const float*)d_in[10];
  const float* b3  = (const float*)d_in[11];
  int n = in_sizes[0] / NF;
  int e = in_sizes[1];
  float* out = (float*)d_out;

  char* ws = (char*)d_ws;
  size_t nbF = (size_t)n * NF * sizeof(float);                       // fp32 [N,128]
  size_t nbB = ((size_t)n * NF * sizeof(bfraw) + 255) / 256 * 256;   // bf16 [N,128]
  float* bufA = (float*)(ws);                 // h0 / A
  float* bufB = (float*)(ws + nbF);           // h1
  bfraw* bufT = (bfraw*)(ws + 2 * nbF);       // per-layer transform out (bf16)
  bfraw* bufC = (bfraw*)(ws + 2 * nbF + nbB); // h2 (bf16)
  char* p = ws + 2 * nbF + 2 * nbB;
  int* rp = (int*)p;     p += (((size_t)(n + 1) * 4) + 255) / 256 * 256;
  int* fill = (int*)p;   p += (((size_t)n * 4) + 255) / 256 * 256;
  int* bsum = (int*)p;   p += 4096;
  unsigned* ecsr = (unsigned*)p;

  hipMemsetAsync(fill, 0, (size_t)n * 4, stream);
  int eb = (e + 255) / 256;
  int nb1 = (n + 1023) / 1024;
  count_kernel<<<eb, 256, 0, stream>>>(tgt, fill, e);
  scan1_kernel<<<nb1, 1024, 0, stream>>>(fill, rp, bsum, n);
  scan2_kernel<<<1, 1024, 0, stream>>>(bsum, nb1, &rp[n]);
  scan3_kernel<<<(n + 255) / 256, 256, 0, stream>>>(rp, fill, bsum, n);
  fill_kernel<<<8 * 256, 256, 0, stream>>>(src, tgt, mw, fill, ecsr, e, n);

  int gb = (n + 63) / 64;
  int ab = (n + 3) / 4;
  // L0: h0 = relu(agg(x@W0) + b0)
  gemm128_kernel<<<gb, 256, 0, stream>>>(x, W0, bufT, n);
  agg128_kernel<true, false, true, false><<<ab, 256, 0, stream>>>(
      bufT, rp, ecsr, b0, nullptr, bufA, n);
  // L1: h1 = relu(agg(h0@W1) + b1) + h0
  gemm128_kernel<<<gb, 256, 0, stream>>>(bufA, W1, bufT, n);
  agg128_kernel<true, true, true, false><<<ab, 256, 0, stream>>>(
      bufT, rp, ecsr, b1, bufA, bufB, n);
  // L2: h2 = relu(agg(h1@W2) + b2) + h1   (stored bf16)
  gemm128_kernel<<<gb, 256, 0, stream>>>(bufB, W2, bufT, n);
  agg128_kernel<true, true, true, true><<<ab, 256, 0, stream>>>(
      bufT, rp, ecsr, b2, bufB, bufC, n);
  // Final: A = agg(h2) ; out = log_softmax(A@W3 + b3)
  agg128_kernel<false, false, false, false><<<ab, 256, 0, stream>>>(
      bufC, rp, ecsr, nullptr, nullptr, bufA, n);
  gemm40_lsm_kernel<<<(n + 255) / 256, 256, 0, stream>>>(bufA, W3, b3, out, n);
}